// Round 1
// baseline (841.839 us; speedup 1.0000x reference)
//
#include <hip/hip_runtime.h>
#include <cstddef>

#define PB 4096  // points per batch
static constexpr float SCALE_F = 0.17677669529663687f;  // 32^-0.5

// ---------------------------------------------------------------------------
// kNN: one wave (64 threads) per query point. Top-32 list lives distributed
// across lanes 0..31 (lane i holds the i-th smallest), sorted ascending by
// (d2, index). Insertion is O(1): ballot to find position, shfl_up to shift.
// Distances in fp64 (exact for fp32 inputs -> ground-truth ordering).
// ---------------------------------------------------------------------------
__global__ __launch_bounds__(64) void knn_kernel(const float* __restrict__ xyz,
                                                 int* __restrict__ idx_out) {
  const int g = blockIdx.x;          // 0 .. B*PB-1
  const int b = g >> 12;
  const int p = g & (PB - 1);
  const int lane = threadIdx.x;
  const float* base = xyz + (size_t)b * PB * 3;
  const double qx = (double)base[p * 3 + 0];
  const double qy = (double)base[p * 3 + 1];
  const double qz = (double)base[p * 3 + 2];
  double list_d = 1e300;  // lanes 0..31: sorted list; lanes 32..63: sentinel
  int list_i = -1;
  for (int c = 0; c < PB / 64; ++c) {
    const int j = (c << 6) + lane;
    const double dx = qx - (double)base[j * 3 + 0];
    const double dy = qy - (double)base[j * 3 + 1];
    const double dz = qz - (double)base[j * 3 + 2];
    const double d2 = dx * dx + dy * dy + dz * dz;
    double worst = __shfl(list_d, 31);
    unsigned long long mask = __ballot(d2 < worst);
    while (mask) {
      const int l = __ffsll(mask) - 1;
      mask &= mask - 1;
      const double v = __shfl(d2, l);       // uniform
      worst = __shfl(list_d, 31);           // refresh (may have shrunk)
      if (v < worst) {                      // uniform branch
        // first strictly-greater position (ties keep earlier/lower index)
        const unsigned long long gt = __ballot((lane < 32) && (list_d > v));
        const int pos = __ffsll(gt) - 1;
        const double pd = __shfl_up(list_d, 1);
        const int pi = __shfl_up(list_i, 1);
        if (lane < 32 && lane >= pos) {
          const bool at = (lane == pos);
          list_d = at ? v : pd;
          list_i = at ? ((c << 6) + l) : pi;
        }
      }
    }
  }
  if (lane < 32) idx_out[(size_t)g * 32 + lane] = list_i;
}

// ---------------------------------------------------------------------------
// Transpose the 256x256 weight matrices once so GEMM loops read coalesced
// WT[j][i] (lane-consecutive i).
// ---------------------------------------------------------------------------
__global__ __launch_bounds__(256) void transpose_w(
    const float* __restrict__ Wq, const float* __restrict__ Wk,
    const float* __restrict__ Wv, const float* __restrict__ W2,
    const float* __restrict__ Wp, float* __restrict__ dst) {
  const int selv = blockIdx.y;
  const float* src = (selv == 0) ? Wq : (selv == 1) ? Wk
                     : (selv == 2) ? Wv : (selv == 3) ? W2 : Wp;
  float* d = dst + (size_t)selv * 65536;
  const int e = blockIdx.x * 256 + threadIdx.x;
  const int i = e >> 8;
  const int j = e & 255;
  d[j * 256 + i] = src[e];
}

// ---------------------------------------------------------------------------
// Core tile: acc[4 rows][8 cols] += A_lds[k0..k0+3][:] * WT[:][i0..i0+7]
// A rows broadcast from LDS (b128, 2-way broadcast pair = free), WT rows
// coalesced from global (L1/L2-hot).
// ---------------------------------------------------------------------------
static __device__ __forceinline__ void gemm_tile_acc(
    const float (*a_lds)[256], const float* __restrict__ WT,
    float acc[4][8], const int k0, const int i0) {
#pragma unroll 2
  for (int j4 = 0; j4 < 64; ++j4) {
    const int jb = j4 << 2;
    float4 wa[4], wb[4];
#pragma unroll
    for (int jj = 0; jj < 4; ++jj) {
      const float* wp = WT + (size_t)(jb + jj) * 256 + i0;
      wa[jj] = *(const float4*)(wp);
      wb[jj] = *(const float4*)(wp + 4);
    }
#pragma unroll
    for (int r = 0; r < 4; ++r) {
      const float4 hv = *(const float4*)(&a_lds[k0 + r][jb]);
      acc[r][0] += hv.x * wa[0].x + hv.y * wa[1].x + hv.z * wa[2].x + hv.w * wa[3].x;
      acc[r][1] += hv.x * wa[0].y + hv.y * wa[1].y + hv.z * wa[2].y + hv.w * wa[3].y;
      acc[r][2] += hv.x * wa[0].z + hv.y * wa[1].z + hv.z * wa[2].z + hv.w * wa[3].z;
      acc[r][3] += hv.x * wa[0].w + hv.y * wa[1].w + hv.z * wa[2].w + hv.w * wa[3].w;
      acc[r][4] += hv.x * wb[0].x + hv.y * wb[1].x + hv.z * wb[2].x + hv.w * wb[3].x;
      acc[r][5] += hv.x * wb[0].y + hv.y * wb[1].y + hv.z * wb[2].y + hv.w * wb[3].y;
      acc[r][6] += hv.x * wb[0].z + hv.y * wb[1].z + hv.z * wb[2].z + hv.w * wb[3].z;
      acc[r][7] += hv.x * wb[0].w + hv.y * wb[1].w + hv.z * wb[2].w + hv.w * wb[3].w;
    }
  }
}

// 32 rows of C = A(rows r0..r0+31) @ WT + bias, one 256-thread block.
static __device__ __forceinline__ void gemm32_rows(
    const float* __restrict__ A, const float* __restrict__ WT,
    const float* __restrict__ bias, float* __restrict__ C,
    const int r0, float (*a_lds)[256]) {
  const int tid = threadIdx.x;
  const float* asrc = A + (size_t)r0 * 256;
#pragma unroll
  for (int t = 0; t < 8; ++t) {
    const int e = (tid << 2) + (t << 10);
    *(float4*)(&a_lds[0][0] + e) = *(const float4*)(asrc + e);
  }
  __syncthreads();
  const int lane = tid & 63;
  const int w = tid >> 6;
  const int il = lane & 31;
  const int kh = lane >> 5;
  const int i0 = il << 3;              // 8 output cols
  const int k0 = (w << 3) + (kh << 2); // 4 output rows
  float acc[4][8];
#pragma unroll
  for (int r = 0; r < 4; ++r)
#pragma unroll
    for (int ci = 0; ci < 8; ++ci) acc[r][ci] = 0.f;
  gemm_tile_acc((const float(*)[256])a_lds, WT, acc, k0, i0);
#pragma unroll
  for (int r = 0; r < 4; ++r) {
    float4 oa, ob;
    oa.x = acc[r][0]; oa.y = acc[r][1]; oa.z = acc[r][2]; oa.w = acc[r][3];
    ob.x = acc[r][4]; ob.y = acc[r][5]; ob.z = acc[r][6]; ob.w = acc[r][7];
    if (bias) {
      const float4 ba = *(const float4*)(bias + i0);
      const float4 bb = *(const float4*)(bias + i0 + 4);
      oa.x += ba.x; oa.y += ba.y; oa.z += ba.z; oa.w += ba.w;
      ob.x += bb.x; ob.y += bb.y; ob.z += bb.z; ob.w += bb.w;
    }
    float* cp = C + (size_t)(r0 + k0 + r) * 256 + i0;
    *(float4*)(cp) = oa;
    *(float4*)(cp + 4) = ob;
  }
}

// q,k,v in one launch (3x grid occupancy vs 3 serialized launches)
__global__ __launch_bounds__(256) void qkv_kernel(
    const float* __restrict__ feats,
    const float* __restrict__ wtq, const float* __restrict__ wtk,
    const float* __restrict__ wtv,
    float* __restrict__ qb, float* __restrict__ kb, float* __restrict__ vb) {
  __shared__ float a_lds[32][256];
  const int sel = blockIdx.x >> 8;
  const int r0 = (blockIdx.x & 255) << 5;
  const float* WT = (sel == 0) ? wtq : (sel == 1) ? wtk : wtv;
  float* C = (sel == 0) ? qb : (sel == 1) ? kb : vb;
  gemm32_rows(feats, WT, nullptr, C, r0, a_lds);
}

__global__ __launch_bounds__(256) void proj_kernel(
    const float* __restrict__ A, const float* __restrict__ wtp,
    const float* __restrict__ bp, float* __restrict__ C) {
  __shared__ float a_lds[32][256];
  gemm32_rows(A, wtp, bp, C, blockIdx.x << 5, a_lds);
}

// ---------------------------------------------------------------------------
// Fused per-point kernel: pos-MLP (h -> pos_bias, the 34 GFLOP GEMM),
// attention scores, softmax over K, weighted output. One block per point.
// pos_bias never touches memory: held in acc[4][8] registers.
// ---------------------------------------------------------------------------
__global__ __launch_bounds__(256) void fused_kernel(
    const float* __restrict__ xyz, const int* __restrict__ nbr_idx,
    const float* __restrict__ qbuf, const float* __restrict__ kbuf,
    const float* __restrict__ vbuf,
    const float* __restrict__ W1, const float* __restrict__ b1,
    const float* __restrict__ WT2, const float* __restrict__ b2v,
    float* __restrict__ o_pre) {
  __shared__ float h_lds[32][256];
  __shared__ float rel[32][3];
  __shared__ int nbr[32];
  __shared__ float sc_lds[32][9];  // pad 9: conflict-free kk-strided reads
  __shared__ float at_lds[32][9];
  __shared__ float ored[8][256];
  const int g = blockIdx.x;
  const int b = g >> 12;
  const int p = g & (PB - 1);
  const int tid = threadIdx.x;
  if (tid < 32) {
    const int j = nbr_idx[(size_t)g * 32 + tid];
    nbr[tid] = j;
    const float* xb = xyz + (size_t)b * PB * 3;
    rel[tid][0] = xb[j * 3 + 0] - xb[p * 3 + 0];
    rel[tid][1] = xb[j * 3 + 1] - xb[p * 3 + 1];
    rel[tid][2] = xb[j * 3 + 2] - xb[p * 3 + 2];
  }
  __syncthreads();
  {  // h[k][i] = relu(relpos @ W1^T + b1), thread owns column i = tid
    const float w0 = W1[tid * 3 + 0];
    const float w1 = W1[tid * 3 + 1];
    const float w2 = W1[tid * 3 + 2];
    const float bb = b1[tid];
#pragma unroll 4
    for (int k = 0; k < 32; ++k) {
      const float hv = bb + rel[k][0] * w0 + rel[k][1] * w1 + rel[k][2] * w2;
      h_lds[k][tid] = fmaxf(hv, 0.f);
    }
  }
  __syncthreads();
  const int lane = tid & 63;
  const int w = tid >> 6;
  const int il = lane & 31;
  const int kh = lane >> 5;
  const int i0 = il << 3;              // 8 feature dims
  const int k0 = (w << 3) + (kh << 2); // 4 neighbors
  const int head = il >> 2;
  float acc[4][8];  // pos_bias for (4 neighbors) x (8 dims)
#pragma unroll
  for (int r = 0; r < 4; ++r)
#pragma unroll
    for (int ci = 0; ci < 8; ++ci) acc[r][ci] = 0.f;
  gemm_tile_acc((const float(*)[256])h_lds, WT2, acc, k0, i0);
  {  // + b2
    const float4 ba = *(const float4*)(b2v + i0);
    const float4 bb = *(const float4*)(b2v + i0 + 4);
#pragma unroll
    for (int r = 0; r < 4; ++r) {
      acc[r][0] += ba.x; acc[r][1] += ba.y; acc[r][2] += ba.z; acc[r][3] += ba.w;
      acc[r][4] += bb.x; acc[r][5] += bb.y; acc[r][6] += bb.z; acc[r][7] += bb.w;
    }
  }
  const float4 qa = *(const float4*)(qbuf + (size_t)g * 256 + i0);
  const float4 qb4 = *(const float4*)(qbuf + (size_t)g * 256 + i0 + 4);
  const size_t kvbase = (size_t)(b << 12) * 256;
  // scores: q . (k_nei + pos_bias) per head, 4-lane shfl reduce (8 dims/lane)
#pragma unroll
  for (int r = 0; r < 4; ++r) {
    const int k = k0 + r;
    const float* krow = kbuf + kvbase + (size_t)nbr[k] * 256;
    const float4 ka = *(const float4*)(krow + i0);
    const float4 kb4 = *(const float4*)(krow + i0 + 4);
    float s = qa.x * (ka.x + acc[r][0]) + qa.y * (ka.y + acc[r][1]) +
              qa.z * (ka.z + acc[r][2]) + qa.w * (ka.w + acc[r][3]) +
              qb4.x * (kb4.x + acc[r][4]) + qb4.y * (kb4.y + acc[r][5]) +
              qb4.z * (kb4.z + acc[r][6]) + qb4.w * (kb4.w + acc[r][7]);
    s += __shfl_xor(s, 1);
    s += __shfl_xor(s, 2);
    if ((lane & 3) == 0) sc_lds[k][head] = s * SCALE_F;
  }
  __syncthreads();
  {  // softmax over K=32 per head: thread (h2, kk), 32-lane shfl reductions
    const int h2 = tid >> 5;
    const int kk = tid & 31;
    const float val = sc_lds[kk][h2];
    float m = val;
#pragma unroll
    for (int off = 16; off; off >>= 1) m = fmaxf(m, __shfl_xor(m, off));
    const float e = __expf(val - m);
    float ssum = e;
#pragma unroll
    for (int off = 16; off; off >>= 1) ssum += __shfl_xor(ssum, off);
    at_lds[kk][h2] = e / ssum;
  }
  __syncthreads();
  float o[8];
#pragma unroll
  for (int ci = 0; ci < 8; ++ci) o[ci] = 0.f;
#pragma unroll
  for (int r = 0; r < 4; ++r) {
    const int k = k0 + r;
    const float aw = at_lds[k][head];
    const float* vrow = vbuf + kvbase + (size_t)nbr[k] * 256;
    const float4 va = *(const float4*)(vrow + i0);
    const float4 vb4 = *(const float4*)(vrow + i0 + 4);
    o[0] += aw * (va.x + acc[r][0]);
    o[1] += aw * (va.y + acc[r][1]);
    o[2] += aw * (va.z + acc[r][2]);
    o[3] += aw * (va.w + acc[r][3]);
    o[4] += aw * (vb4.x + acc[r][4]);
    o[5] += aw * (vb4.y + acc[r][5]);
    o[6] += aw * (vb4.z + acc[r][6]);
    o[7] += aw * (vb4.w + acc[r][7]);
  }
  const int orow = (w << 1) | kh;
  *(float4*)(&ored[orow][i0]) = make_float4(o[0], o[1], o[2], o[3]);
  *(float4*)(&ored[orow][i0 + 4]) = make_float4(o[4], o[5], o[6], o[7]);
  __syncthreads();
  {
    float s = 0.f;
#pragma unroll
    for (int rr = 0; rr < 8; ++rr) s += ored[rr][tid];
    o_pre[(size_t)g * 256 + tid] = s;
  }
}

// ---------------------------------------------------------------------------
extern "C" void kernel_launch(void* const* d_in, const int* in_sizes, int n_in,
                              void* d_out, int out_size, void* d_ws, size_t ws_size,
                              hipStream_t stream) {
  (void)in_sizes; (void)n_in; (void)out_size; (void)ws_size;
  const float* xyz   = (const float*)d_in[0];
  const float* feats = (const float*)d_in[1];
  const float* Wq    = (const float*)d_in[2];
  const float* Wk    = (const float*)d_in[3];
  const float* Wv    = (const float*)d_in[4];
  const float* Wp    = (const float*)d_in[5];
  const float* bp    = (const float*)d_in[6];
  const float* W1    = (const float*)d_in[7];
  const float* b1    = (const float*)d_in[8];
  const float* W2    = (const float*)d_in[9];
  const float* b2    = (const float*)d_in[10];
  float* out = (float*)d_out;

  // workspace layout (floats): [idx:262144][q:2M][k:2M][v:2M][o_pre:2M][WT:5*65536]
  int* idxw  = (int*)d_ws;
  float* wsf = (float*)d_ws;
  float* qb = wsf + 262144;
  float* kb = qb + 2097152;
  float* vb = kb + 2097152;
  float* op = vb + 2097152;
  float* wt = op + 2097152;
  float* wtq = wt;
  float* wtk = wt + 65536;
  float* wtv = wt + 131072;
  float* wt2 = wt + 196608;
  float* wtp = wt + 262144;

  hipLaunchKernelGGL(transpose_w, dim3(256, 5), dim3(256), 0, stream,
                     Wq, Wk, Wv, W2, Wp, wt);
  hipLaunchKernelGGL(knn_kernel, dim3(2 * PB), dim3(64), 0, stream, xyz, idxw);
  hipLaunchKernelGGL(qkv_kernel, dim3(768), dim3(256), 0, stream,
                     feats, wtq, wtk, wtv, qb, kb, vb);
  hipLaunchKernelGGL(fused_kernel, dim3(2 * PB), dim3(256), 0, stream,
                     xyz, idxw, qb, kb, vb, W1, b1, wt2, b2, op);
  hipLaunchKernelGGL(proj_kernel, dim3(256), dim3(256), 0, stream,
                     op, wtp, bp, out);
}

// Round 2
// 419.653 us; speedup vs baseline: 2.0060x; 2.0060x over previous
//
#include <hip/hip_runtime.h>
#include <cstddef>

#define PB 4096  // points per batch
static constexpr float SCALE_F = 0.17677669529663687f;  // 32^-0.5

typedef __attribute__((ext_vector_type(8))) short bf16x8;
typedef __attribute__((ext_vector_type(4))) float f32x4;

static __device__ __forceinline__ unsigned short f2bf(float x) {
  unsigned u = __builtin_bit_cast(unsigned, x);
  u += 0x7fffu + ((u >> 16) & 1u);  // RNE
  return (unsigned short)(u >> 16);
}

// ---------------------------------------------------------------------------
// kNN: one wave per query point; sorted top-32 distributed over lanes 0..31.
// fp64 distances = ground-truth ordering.
// ---------------------------------------------------------------------------
__global__ __launch_bounds__(64) void knn_kernel(const float* __restrict__ xyz,
                                                 int* __restrict__ idx_out) {
  const int g = blockIdx.x;          // 0 .. B*PB-1
  const int b = g >> 12;
  const int p = g & (PB - 1);
  const int lane = threadIdx.x;
  const float* base = xyz + (size_t)b * PB * 3;
  const double qx = (double)base[p * 3 + 0];
  const double qy = (double)base[p * 3 + 1];
  const double qz = (double)base[p * 3 + 2];
  double list_d = 1e300;
  int list_i = -1;
  for (int c = 0; c < PB / 64; ++c) {
    const int j = (c << 6) + lane;
    const double dx = qx - (double)base[j * 3 + 0];
    const double dy = qy - (double)base[j * 3 + 1];
    const double dz = qz - (double)base[j * 3 + 2];
    const double d2 = dx * dx + dy * dy + dz * dz;
    double worst = __shfl(list_d, 31);
    unsigned long long mask = __ballot(d2 < worst);
    while (mask) {
      const int l = __ffsll(mask) - 1;
      mask &= mask - 1;
      const double v = __shfl(d2, l);
      worst = __shfl(list_d, 31);
      if (v < worst) {
        const unsigned long long gt = __ballot((lane < 32) && (list_d > v));
        const int pos = __ffsll(gt) - 1;
        const double pd = __shfl_up(list_d, 1);
        const int pi = __shfl_up(list_i, 1);
        if (lane < 32 && lane >= pos) {
          const bool at = (lane == pos);
          list_d = at ? v : pd;
          list_i = at ? ((c << 6) + l) : pi;
        }
      }
    }
  }
  if (lane < 32) idx_out[(size_t)g * 32 + lane] = list_i;
}

// ---------------------------------------------------------------------------
// Weight prep: transpose Wq/Wk/Wv/Wp (fp32 GEMMs read WT coalesced) and
// convert W2 (row-major, K-contiguous) to bf16 for MFMA B-fragments.
// ---------------------------------------------------------------------------
__global__ __launch_bounds__(256) void transpose_w(
    const float* __restrict__ Wq, const float* __restrict__ Wk,
    const float* __restrict__ Wv, const float* __restrict__ Wp,
    float* __restrict__ dst) {
  const int selv = blockIdx.y;
  const float* src = (selv == 0) ? Wq : (selv == 1) ? Wk : (selv == 2) ? Wv : Wp;
  float* d = dst + (size_t)selv * 65536;
  const int e = blockIdx.x * 256 + threadIdx.x;
  const int i = e >> 8;
  const int j = e & 255;
  d[j * 256 + i] = src[e];
}

__global__ __launch_bounds__(256) void convert_w2(const float* __restrict__ W2,
                                                  unsigned short* __restrict__ dst) {
  const int e = blockIdx.x * 256 + threadIdx.x;
  dst[e] = f2bf(W2[e]);
}

// ---------------------------------------------------------------------------
// fp32 tile GEMM for qkv/proj (32 rows per block), unchanged from round 0.
// ---------------------------------------------------------------------------
static __device__ __forceinline__ void gemm_tile_acc(
    const float (*a_lds)[256], const float* __restrict__ WT,
    float acc[4][8], const int k0, const int i0) {
#pragma unroll 2
  for (int j4 = 0; j4 < 64; ++j4) {
    const int jb = j4 << 2;
    float4 wa[4], wb[4];
#pragma unroll
    for (int jj = 0; jj < 4; ++jj) {
      const float* wp = WT + (size_t)(jb + jj) * 256 + i0;
      wa[jj] = *(const float4*)(wp);
      wb[jj] = *(const float4*)(wp + 4);
    }
#pragma unroll
    for (int r = 0; r < 4; ++r) {
      const float4 hv = *(const float4*)(&a_lds[k0 + r][jb]);
      acc[r][0] += hv.x * wa[0].x + hv.y * wa[1].x + hv.z * wa[2].x + hv.w * wa[3].x;
      acc[r][1] += hv.x * wa[0].y + hv.y * wa[1].y + hv.z * wa[2].y + hv.w * wa[3].y;
      acc[r][2] += hv.x * wa[0].z + hv.y * wa[1].z + hv.z * wa[2].z + hv.w * wa[3].z;
      acc[r][3] += hv.x * wa[0].w + hv.y * wa[1].w + hv.z * wa[2].w + hv.w * wa[3].w;
      acc[r][4] += hv.x * wb[0].x + hv.y * wb[1].x + hv.z * wb[2].x + hv.w * wb[3].x;
      acc[r][5] += hv.x * wb[0].y + hv.y * wb[1].y + hv.z * wb[2].y + hv.w * wb[3].y;
      acc[r][6] += hv.x * wb[0].z + hv.y * wb[1].z + hv.z * wb[2].z + hv.w * wb[3].z;
      acc[r][7] += hv.x * wb[0].w + hv.y * wb[1].w + hv.z * wb[2].w + hv.w * wb[3].w;
    }
  }
}

static __device__ __forceinline__ void gemm32_rows(
    const float* __restrict__ A, const float* __restrict__ WT,
    const float* __restrict__ bias, float* __restrict__ C,
    const int r0, float (*a_lds)[256]) {
  const int tid = threadIdx.x;
  const float* asrc = A + (size_t)r0 * 256;
#pragma unroll
  for (int t = 0; t < 8; ++t) {
    const int e = (tid << 2) + (t << 10);
    *(float4*)(&a_lds[0][0] + e) = *(const float4*)(asrc + e);
  }
  __syncthreads();
  const int lane = tid & 63;
  const int w = tid >> 6;
  const int il = lane & 31;
  const int kh = lane >> 5;
  const int i0 = il << 3;
  const int k0 = (w << 3) + (kh << 2);
  float acc[4][8];
#pragma unroll
  for (int r = 0; r < 4; ++r)
#pragma unroll
    for (int ci = 0; ci < 8; ++ci) acc[r][ci] = 0.f;
  gemm_tile_acc((const float(*)[256])a_lds, WT, acc, k0, i0);
#pragma unroll
  for (int r = 0; r < 4; ++r) {
    float4 oa, ob;
    oa.x = acc[r][0]; oa.y = acc[r][1]; oa.z = acc[r][2]; oa.w = acc[r][3];
    ob.x = acc[r][4]; ob.y = acc[r][5]; ob.z = acc[r][6]; ob.w = acc[r][7];
    if (bias) {
      const float4 ba = *(const float4*)(bias + i0);
      const float4 bb = *(const float4*)(bias + i0 + 4);
      oa.x += ba.x; oa.y += ba.y; oa.z += ba.z; oa.w += ba.w;
      ob.x += bb.x; ob.y += bb.y; ob.z += bb.z; ob.w += bb.w;
    }
    float* cp = C + (size_t)(r0 + k0 + r) * 256 + i0;
    *(float4*)(cp) = oa;
    *(float4*)(cp + 4) = ob;
  }
}

__global__ __launch_bounds__(256) void qkv_kernel(
    const float* __restrict__ feats,
    const float* __restrict__ wtq, const float* __restrict__ wtk,
    const float* __restrict__ wtv,
    float* __restrict__ qb, float* __restrict__ kb, float* __restrict__ vb) {
  __shared__ float a_lds[32][256];
  const int sel = blockIdx.x >> 8;
  const int r0 = (blockIdx.x & 255) << 5;
  const float* WT = (sel == 0) ? wtq : (sel == 1) ? wtk : wtv;
  float* C = (sel == 0) ? qb : (sel == 1) ? kb : vb;
  gemm32_rows(feats, WT, nullptr, C, r0, a_lds);
}

__global__ __launch_bounds__(256) void proj_kernel(
    const float* __restrict__ A, const float* __restrict__ wtp,
    const float* __restrict__ bp, float* __restrict__ C) {
  __shared__ float a_lds[32][256];
  gemm32_rows(A, wtp, bp, C, blockIdx.x << 5, a_lds);
}

// ---------------------------------------------------------------------------
// MFMA fused kernel: 2 points per block (M = 64 neighbor-rows), 4 waves, each
// wave owns 64 N-columns. pos_bias = relu(relpos@W1^T)@W2^T via
// v_mfma_f32_16x16x32_bf16, accumulator stays in registers in D-layout:
//   m = mt*16 + (lane>>4)*4 + reg,  n = w*64 + nt*16 + (lane&15)
// h is staged in LDS (bf16, XOR-swizzled: byte ^= (row&7)<<4) for the
// A-fragment ds_read_b128; B-fragments come straight from row-major bf16 W2
// (L2-resident). Scores/softmax/output use shuffle reductions on that layout.
// ---------------------------------------------------------------------------
__global__ __launch_bounds__(256) void fused_kernel(
    const float* __restrict__ xyz, const int* __restrict__ nbr_idx,
    const float* __restrict__ qbuf, const float* __restrict__ kbuf,
    const float* __restrict__ vbuf,
    const float* __restrict__ W1, const float* __restrict__ b1,
    const unsigned short* __restrict__ w2bf, const float* __restrict__ b2,
    float* __restrict__ o_pre) {
  __shared__ unsigned short h_lds[64 * 256];  // 32 KB, swizzled row-major
  __shared__ float q_lds[512];
  __shared__ float rel[2][32][3];
  __shared__ int nbr[2][32];
  __shared__ float sc_lds[2][32][9];
  __shared__ float at_lds[2][32][9];

  const int blk = blockIdx.x;        // 0 .. 4095
  const int g0 = blk << 1;           // first of 2 points
  const int b = g0 >> 12;
  const int tid = threadIdx.x;

  // ---- phase 0: neighbor indices, relpos, q staging
  if (tid < 64) {
    const int pt = tid >> 5, kk = tid & 31;
    const int gg = g0 + pt;
    const int p = gg & (PB - 1);
    const int j = nbr_idx[(size_t)gg * 32 + kk];
    nbr[pt][kk] = j;
    const float* xb = xyz + (size_t)b * PB * 3;
    rel[pt][kk][0] = xb[j * 3 + 0] - xb[p * 3 + 0];
    rel[pt][kk][1] = xb[j * 3 + 1] - xb[p * 3 + 1];
    rel[pt][kk][2] = xb[j * 3 + 2] - xb[p * 3 + 2];
  }
  q_lds[tid]       = qbuf[(size_t)g0 * 256 + tid];
  q_lds[tid + 256] = qbuf[(size_t)g0 * 256 + tid + 256];
  __syncthreads();

  // ---- phase 1: h = relu(relpos @ W1^T + b1) -> LDS bf16 (swizzled)
  {
    const int pt = tid >> 7;          // uniform per wave
    const int cp = tid & 127;         // column pair
    const int c0 = cp << 1;
    const float w00 = W1[c0 * 3 + 0], w01 = W1[c0 * 3 + 1], w02 = W1[c0 * 3 + 2];
    const float w10 = W1[c0 * 3 + 3], w11 = W1[c0 * 3 + 4], w12 = W1[c0 * 3 + 5];
    const float bb0 = b1[c0], bb1 = b1[c0 + 1];
#pragma unroll 4
    for (int rl = 0; rl < 32; ++rl) {
      const int rr = (pt << 5) + rl;
      const float rx = rel[pt][rl][0], ry = rel[pt][rl][1], rz = rel[pt][rl][2];
      const float h0 = fmaxf(bb0 + rx * w00 + ry * w01 + rz * w02, 0.f);
      const float h1 = fmaxf(bb1 + rx * w10 + ry * w11 + rz * w12, 0.f);
      const unsigned pk = (unsigned)f2bf(h0) | ((unsigned)f2bf(h1) << 16);
      *(unsigned*)((char*)h_lds + rr * 512 + (((unsigned)c0 << 1) ^ ((rr & 7) << 4))) = pk;
    }
  }
  __syncthreads();

  const int lane = tid & 63;
  const int w = tid >> 6;
  const int il = lane & 15;
  const int q4 = lane >> 4;

  // ---- phase 2: pos_bias MFMA, acc[mt][nt] over K=256
  f32x4 acc[4][4];
#pragma unroll
  for (int mt = 0; mt < 4; ++mt)
#pragma unroll
    for (int nt = 0; nt < 4; ++nt) acc[mt][nt] = (f32x4){0.f, 0.f, 0.f, 0.f};
#pragma unroll 2
  for (int ks = 0; ks < 8; ++ks) {
    bf16x8 bfr[4], afr[4];
#pragma unroll
    for (int nt = 0; nt < 4; ++nt) {
      const int n = (w << 6) + (nt << 4) + il;
      bfr[nt] = *(const bf16x8*)(w2bf + (size_t)n * 256 + (ks << 5) + (q4 << 3));
    }
#pragma unroll
    for (int mt = 0; mt < 4; ++mt) {
      const int row = (mt << 4) + il;
      const int byte = row * 512 + ((((ks << 5) + (q4 << 3)) << 1) ^ ((row & 7) << 4));
      afr[mt] = *(const bf16x8*)((const char*)h_lds + byte);
    }
#pragma unroll
    for (int mt = 0; mt < 4; ++mt)
#pragma unroll
      for (int nt = 0; nt < 4; ++nt)
        acc[mt][nt] = __builtin_amdgcn_mfma_f32_16x16x32_bf16(
            afr[mt], bfr[nt], acc[mt][nt], 0, 0, 0);
  }
  // + b2 (broadcast over rows)
#pragma unroll
  for (int nt = 0; nt < 4; ++nt) {
    const float bv = b2[(w << 6) + (nt << 4) + il];
#pragma unroll
    for (int mt = 0; mt < 4; ++mt)
#pragma unroll
      for (int r = 0; r < 4; ++r) acc[mt][nt][r] += bv;
  }

  const size_t kvbase = (size_t)(b << 12) * 256;

  // ---- phase 3: scores s[pt][k][head] = SCALE * sum_d q[d]*(k_nei[d]+pb[d])
#pragma unroll
  for (int mt = 0; mt < 4; ++mt) {
    const int pt = mt >> 1;
#pragma unroll
    for (int r = 0; r < 4; ++r) {
      const int k = ((mt & 1) << 4) + (q4 << 2) + r;
      const int j = nbr[pt][k];
      const float* krow = kbuf + kvbase + (size_t)j * 256;
      float sA = 0.f, sB = 0.f;
#pragma unroll
      for (int nt = 0; nt < 4; ++nt) {
        const int d = (w << 6) + (nt << 4) + il;
        const float t = q_lds[(pt << 8) + d] * (krow[d] + acc[mt][nt][r]);
        if (nt < 2) sA += t; else sB += t;
      }
#pragma unroll
      for (int off = 1; off <= 8; off <<= 1) {
        sA += __shfl_xor(sA, off);
        sB += __shfl_xor(sB, off);
      }
      if (il == 0) {
        sc_lds[pt][k][(w << 1)]     = sA * SCALE_F;
        sc_lds[pt][k][(w << 1) + 1] = sB * SCALE_F;
      }
    }
  }
  __syncthreads();

  // ---- phase 4: softmax over K=32 per (pt, head)
  {
    const int kk = tid & 31;
    const int head = (tid >> 5) & 7;
#pragma unroll
    for (int pt = 0; pt < 2; ++pt) {
      const float val = sc_lds[pt][kk][head];
      float m = val;
#pragma unroll
      for (int off = 16; off; off >>= 1) m = fmaxf(m, __shfl_xor(m, off));
      const float e = __expf(val - m);
      float s = e;
#pragma unroll
      for (int off = 16; off; off >>= 1) s += __shfl_xor(s, off);
      at_lds[pt][kk][head] = e / s;
    }
  }
  __syncthreads();

  // ---- phase 5: out[pt][d] = sum_k attn * (v_nei + pb)
  float o[2][4];
#pragma unroll
  for (int pt = 0; pt < 2; ++pt)
#pragma unroll
    for (int nt = 0; nt < 4; ++nt) o[pt][nt] = 0.f;
#pragma unroll
  for (int mt = 0; mt < 4; ++mt) {
    const int pt = mt >> 1;
#pragma unroll
    for (int r = 0; r < 4; ++r) {
      const int k = ((mt & 1) << 4) + (q4 << 2) + r;
      const int j = nbr[pt][k];
      const float* vrow = vbuf + kvbase + (size_t)j * 256;
      const float awA = at_lds[pt][k][(w << 1)];
      const float awB = at_lds[pt][k][(w << 1) + 1];
#pragma unroll
      for (int nt = 0; nt < 4; ++nt) {
        const int d = (w << 6) + (nt << 4) + il;
        const float aw = (nt < 2) ? awA : awB;
        o[pt][nt] += aw * (vrow[d] + acc[mt][nt][r]);
      }
    }
  }
#pragma unroll
  for (int pt = 0; pt < 2; ++pt)
#pragma unroll
    for (int nt = 0; nt < 4; ++nt) {
      float v = o[pt][nt];
      v += __shfl_xor(v, 16);
      v += __shfl_xor(v, 32);
      if (q4 == 0)
        o_pre[(size_t)(g0 + pt) * 256 + (w << 6) + (nt << 4) + il] = v;
    }
}

// ---------------------------------------------------------------------------
extern "C" void kernel_launch(void* const* d_in, const int* in_sizes, int n_in,
                              void* d_out, int out_size, void* d_ws, size_t ws_size,
                              hipStream_t stream) {
  (void)in_sizes; (void)n_in; (void)out_size; (void)ws_size;
  const float* xyz   = (const float*)d_in[0];
  const float* feats = (const float*)d_in[1];
  const float* Wq    = (const float*)d_in[2];
  const float* Wk    = (const float*)d_in[3];
  const float* Wv    = (const float*)d_in[4];
  const float* Wp    = (const float*)d_in[5];
  const float* bp    = (const float*)d_in[6];
  const float* W1    = (const float*)d_in[7];
  const float* b1    = (const float*)d_in[8];
  const float* W2    = (const float*)d_in[9];
  const float* b2    = (const float*)d_in[10];
  float* out = (float*)d_out;

  // ws floats: [idx:262144][q:2M][k:2M][v:2M][op:2M][wt:4*65536][w2bf:32768]
  int* idxw  = (int*)d_ws;
  float* wsf = (float*)d_ws;
  float* qb = wsf + 262144;
  float* kb = qb + 2097152;
  float* vb = kb + 2097152;
  float* op = vb + 2097152;
  float* wt = op + 2097152;
  float* wtq = wt;
  float* wtk = wt + 65536;
  float* wtv = wt + 131072;
  float* wtp = wt + 196608;
  unsigned short* w2bf = (unsigned short*)(wt + 262144);

  hipLaunchKernelGGL(transpose_w, dim3(256, 4), dim3(256), 0, stream,
                     Wq, Wk, Wv, Wp, wt);
  hipLaunchKernelGGL(convert_w2, dim3(256), dim3(256), 0, stream, W2, w2bf);
  hipLaunchKernelGGL(knn_kernel, dim3(2 * PB), dim3(64), 0, stream, xyz, idxw);
  hipLaunchKernelGGL(qkv_kernel, dim3(768), dim3(256), 0, stream,
                     feats, wtq, wtk, wtv, qb, kb, vb);
  hipLaunchKernelGGL(fused_kernel, dim3(PB), dim3(256), 0, stream,
                     xyz, idxw, qb, kb, vb, W1, b1, w2bf, b2, op);
  hipLaunchKernelGGL(proj_kernel, dim3(256), dim3(256), 0, stream,
                     op, wtp, bp, out);
}

// Round 3
// 299.477 us; speedup vs baseline: 2.8110x; 1.4013x over previous
//
#include <hip/hip_runtime.h>
#include <cstddef>

#define PB 4096  // points per batch
static constexpr float SCALE_F = 0.17677669529663687f;  // 32^-0.5

typedef __attribute__((ext_vector_type(8))) short bf16x8;
typedef __attribute__((ext_vector_type(4))) float f32x4;

static __device__ __forceinline__ unsigned short f2bf(float x) {
  unsigned u = __builtin_bit_cast(unsigned, x);
  u += 0x7fffu + ((u >> 16) & 1u);  // RNE
  return (unsigned short)(u >> 16);
}
static __device__ __forceinline__ float bf2f(unsigned short h) {
  return __builtin_bit_cast(float, (unsigned)h << 16);
}

// ---------------------------------------------------------------------------
// kNN: one wave per query; sorted top-32 distributed over lanes 0..31.
// fp32 distances with explicit rounding = exactly the reference's arithmetic
// ((dx^2+dy^2)+dz^2, no FMA contraction); ties resolved by lower index first
// (lax.top_k stable order).
// ---------------------------------------------------------------------------
__global__ __launch_bounds__(64) void knn_kernel(const float* __restrict__ xyz,
                                                 int* __restrict__ idx_out) {
  const int g = blockIdx.x;          // 0 .. B*PB-1
  const int b = g >> 12;
  const int p = g & (PB - 1);
  const int lane = threadIdx.x;
  const float* base = xyz + (size_t)b * PB * 3;
  const float qx = base[p * 3 + 0];
  const float qy = base[p * 3 + 1];
  const float qz = base[p * 3 + 2];
  float list_d = 3.4e38f;  // lanes 0..31 hold the sorted list
  int list_i = -1;
  for (int c = 0; c < PB / 64; ++c) {
    const int j = (c << 6) + lane;
    const float dx = __fsub_rn(qx, base[j * 3 + 0]);
    const float dy = __fsub_rn(qy, base[j * 3 + 1]);
    const float dz = __fsub_rn(qz, base[j * 3 + 2]);
    const float d2 = __fadd_rn(__fadd_rn(__fmul_rn(dx, dx), __fmul_rn(dy, dy)),
                               __fmul_rn(dz, dz));
    float worst = __shfl(list_d, 31);
    unsigned long long mask = __ballot(d2 < worst);
    while (mask) {
      const int l = __ffsll(mask) - 1;
      mask &= mask - 1;
      const float v = __shfl(d2, l);
      worst = __shfl(list_d, 31);
      if (v < worst) {
        const unsigned long long gt = __ballot((lane < 32) && (list_d > v));
        const int pos = __ffsll(gt) - 1;
        const float pd = __shfl_up(list_d, 1);
        const int pi = __shfl_up(list_i, 1);
        if (lane < 32 && lane >= pos) {
          const bool at = (lane == pos);
          list_d = at ? v : pd;
          list_i = at ? ((c << 6) + l) : pi;
        }
      }
    }
  }
  if (lane < 32) idx_out[(size_t)g * 32 + lane] = list_i;
}

// ---------------------------------------------------------------------------
// Weight prep: bf16 hi/lo split of Wq,Wk,Wv,W2,Wp (row-major, K-contiguous —
// exactly the MFMA B-fragment layout, no transpose needed).
// ---------------------------------------------------------------------------
__global__ __launch_bounds__(256) void prep_w(
    const float* __restrict__ Wq, const float* __restrict__ Wk,
    const float* __restrict__ Wv, const float* __restrict__ W2,
    const float* __restrict__ Wp,
    unsigned short* __restrict__ whi, unsigned short* __restrict__ wlo) {
  const int e = blockIdx.x * 256 + threadIdx.x;   // 0 .. 327679
  const int m = e >> 16;
  const int off = e & 65535;
  const float* src = (m == 0) ? Wq : (m == 1) ? Wk : (m == 2) ? Wv
                     : (m == 3) ? W2 : Wp;
  const float x = src[off];
  const unsigned short hi = f2bf(x);
  whi[e] = hi;
  wlo[e] = f2bf(x - bf2f(hi));
}

// ---------------------------------------------------------------------------
// bf16x3 MFMA GEMM: C[r0..r0+31][:] = A @ W^T (+bias), W given row-major
// [n][k] as hi/lo bf16. D = Ah*Wh + Al*Wh + Ah*Wl  (err ~2^-18 rel).
// 256 threads: 4 waves x 64 N-cols; A staged in LDS hi/lo, XOR-swizzled.
// ---------------------------------------------------------------------------
static __device__ __forceinline__ void gemm32_mfma(
    const float* __restrict__ A, const unsigned short* __restrict__ wh,
    const unsigned short* __restrict__ wl, const float* __restrict__ bias,
    float* __restrict__ C, const int r0,
    unsigned short* ah, unsigned short* al) {
  const int tid = threadIdx.x;
#pragma unroll
  for (int t = 0; t < 8; ++t) {
    const int idx4 = (t << 8) + tid;     // 2048 float4-slots = 32 rows x 64
    const int row = idx4 >> 6;
    const int c4 = idx4 & 63;
    const float4 v = *(const float4*)(A + (size_t)(r0 + row) * 256 + (c4 << 2));
    const unsigned short h0 = f2bf(v.x), h1 = f2bf(v.y);
    const unsigned short h2 = f2bf(v.z), h3 = f2bf(v.w);
    const unsigned short l0 = f2bf(v.x - bf2f(h0)), l1 = f2bf(v.y - bf2f(h1));
    const unsigned short l2 = f2bf(v.z - bf2f(h2)), l3 = f2bf(v.w - bf2f(h3));
    const int base = (row << 9) + ((c4 << 3) ^ ((row & 7) << 4));
    *(uint2*)((char*)ah + base) =
        make_uint2((unsigned)h0 | ((unsigned)h1 << 16),
                   (unsigned)h2 | ((unsigned)h3 << 16));
    *(uint2*)((char*)al + base) =
        make_uint2((unsigned)l0 | ((unsigned)l1 << 16),
                   (unsigned)l2 | ((unsigned)l3 << 16));
  }
  __syncthreads();
  const int lane = tid & 63;
  const int w = tid >> 6;
  const int il = lane & 15;
  const int q4 = lane >> 4;
  f32x4 acc[2][4];
#pragma unroll
  for (int mt = 0; mt < 2; ++mt)
#pragma unroll
    for (int nt = 0; nt < 4; ++nt) acc[mt][nt] = (f32x4){0.f, 0.f, 0.f, 0.f};
#pragma unroll 2
  for (int ks = 0; ks < 8; ++ks) {
    bf16x8 bh[4], bl[4], a0[2], a1[2];
#pragma unroll
    for (int nt = 0; nt < 4; ++nt) {
      const int n = (w << 6) + (nt << 4) + il;
      const size_t off = (size_t)n * 256 + (ks << 5) + (q4 << 3);
      bh[nt] = *(const bf16x8*)(wh + off);
      bl[nt] = *(const bf16x8*)(wl + off);
    }
#pragma unroll
    for (int mt = 0; mt < 2; ++mt) {
      const int row = (mt << 4) + il;
      const int byte = (row << 9) + ((((ks << 5) + (q4 << 3)) << 1) ^ ((row & 7) << 4));
      a0[mt] = *(const bf16x8*)((const char*)ah + byte);
      a1[mt] = *(const bf16x8*)((const char*)al + byte);
    }
#pragma unroll
    for (int mt = 0; mt < 2; ++mt)
#pragma unroll
      for (int nt = 0; nt < 4; ++nt) {
        acc[mt][nt] = __builtin_amdgcn_mfma_f32_16x16x32_bf16(a0[mt], bh[nt], acc[mt][nt], 0, 0, 0);
        acc[mt][nt] = __builtin_amdgcn_mfma_f32_16x16x32_bf16(a1[mt], bh[nt], acc[mt][nt], 0, 0, 0);
        acc[mt][nt] = __builtin_amdgcn_mfma_f32_16x16x32_bf16(a0[mt], bl[nt], acc[mt][nt], 0, 0, 0);
      }
  }
#pragma unroll
  for (int mt = 0; mt < 2; ++mt)
#pragma unroll
    for (int nt = 0; nt < 4; ++nt) {
      const int col = (w << 6) + (nt << 4) + il;
      const float bv = bias ? bias[col] : 0.f;
#pragma unroll
      for (int r = 0; r < 4; ++r)
        C[(size_t)(r0 + (mt << 4) + (q4 << 2) + r) * 256 + col] = acc[mt][nt][r] + bv;
    }
}

__global__ __launch_bounds__(256) void qkv_mfma(
    const float* __restrict__ feats,
    const unsigned short* __restrict__ whi, const unsigned short* __restrict__ wlo,
    float* __restrict__ qb, float* __restrict__ kb, float* __restrict__ vb) {
  __shared__ unsigned short ah[32 * 256];
  __shared__ unsigned short al[32 * 256];
  const int bid = blockIdx.x;
  const int sel = bid % 3;
  const int r0 = (bid / 3) << 5;
  const unsigned short* wh = whi + (size_t)sel * 65536;
  const unsigned short* wl = wlo + (size_t)sel * 65536;
  float* C = (sel == 0) ? qb : (sel == 1) ? kb : vb;
  gemm32_mfma(feats, wh, wl, nullptr, C, r0, ah, al);
}

__global__ __launch_bounds__(256) void proj_mfma(
    const float* __restrict__ A,
    const unsigned short* __restrict__ whi, const unsigned short* __restrict__ wlo,
    const float* __restrict__ bp, float* __restrict__ C) {
  __shared__ unsigned short ah[32 * 256];
  __shared__ unsigned short al[32 * 256];
  gemm32_mfma(A, whi, wlo, bp, C, blockIdx.x << 5, ah, al);
}

// ---------------------------------------------------------------------------
// MFMA fused kernel: 2 points per block, 512 threads = 8 waves, each wave
// owns 32 N-cols (exactly one head). pos_bias accumulator = acc[4 mt][2 nt]
// f32x4 (32 VGPR) -> ~4 waves/SIMD occupancy. D-layout:
//   m = mt*16 + q4*4 + r (neighbor row), n = w*32 + nt*16 + il (feature dim)
// ---------------------------------------------------------------------------
__global__ __launch_bounds__(512) void fused_kernel(
    const float* __restrict__ xyz, const int* __restrict__ nbr_idx,
    const float* __restrict__ qbuf, const float* __restrict__ kbuf,
    const float* __restrict__ vbuf,
    const float* __restrict__ W1, const float* __restrict__ b1,
    const unsigned short* __restrict__ w2hi, const float* __restrict__ b2,
    float* __restrict__ o_pre) {
  __shared__ unsigned short h_lds[64 * 256];  // 32 KB, swizzled
  __shared__ float q_lds[512];
  __shared__ float rel[2][32][3];
  __shared__ int nbr[2][32];
  __shared__ float sc_lds[2][32][9];
  __shared__ float at_lds[2][32][9];

  const int g0 = blockIdx.x << 1;
  const int b = g0 >> 12;
  const int tid = threadIdx.x;

  // ---- phase 0: neighbors, relpos, q
  if (tid < 64) {
    const int pt = tid >> 5, kk = tid & 31;
    const int gg = g0 + pt;
    const int p = gg & (PB - 1);
    const int j = nbr_idx[(size_t)gg * 32 + kk];
    nbr[pt][kk] = j;
    const float* xb = xyz + (size_t)b * PB * 3;
    rel[pt][kk][0] = xb[j * 3 + 0] - xb[p * 3 + 0];
    rel[pt][kk][1] = xb[j * 3 + 1] - xb[p * 3 + 1];
    rel[pt][kk][2] = xb[j * 3 + 2] - xb[p * 3 + 2];
  }
  q_lds[tid] = qbuf[(size_t)g0 * 256 + tid];
  __syncthreads();

  // ---- phase 1: h = relu(relpos @ W1^T + b1) -> LDS bf16 (swizzled)
  {
    const int pt = tid >> 8;
    const int half = (tid >> 7) & 1;
    const int cp = tid & 127;
    const int c0 = cp << 1;
    const float w00 = W1[c0 * 3 + 0], w01 = W1[c0 * 3 + 1], w02 = W1[c0 * 3 + 2];
    const float w10 = W1[c0 * 3 + 3], w11 = W1[c0 * 3 + 4], w12 = W1[c0 * 3 + 5];
    const float bb0 = b1[c0], bb1 = b1[c0 + 1];
#pragma unroll 4
    for (int rl = 0; rl < 16; ++rl) {
      const int rloc = (half << 4) + rl;
      const int rr = (pt << 5) + rloc;
      const float rx = rel[pt][rloc][0], ry = rel[pt][rloc][1], rz = rel[pt][rloc][2];
      const float h0 = fmaxf(bb0 + rx * w00 + ry * w01 + rz * w02, 0.f);
      const float h1 = fmaxf(bb1 + rx * w10 + ry * w11 + rz * w12, 0.f);
      const unsigned pk = (unsigned)f2bf(h0) | ((unsigned)f2bf(h1) << 16);
      *(unsigned*)((char*)h_lds + (rr << 9) + (((unsigned)c0 << 1) ^ ((rr & 7) << 4))) = pk;
    }
  }
  __syncthreads();

  const int lane = tid & 63;
  const int w = tid >> 6;           // wave id == head id
  const int il = lane & 15;
  const int q4 = lane >> 4;

  // ---- phase 2: pos_bias MFMA over K=256
  f32x4 acc[4][2];
#pragma unroll
  for (int mt = 0; mt < 4; ++mt)
#pragma unroll
    for (int nt = 0; nt < 2; ++nt) acc[mt][nt] = (f32x4){0.f, 0.f, 0.f, 0.f};
#pragma unroll 2
  for (int ks = 0; ks < 8; ++ks) {
    bf16x8 bfr[2], afr[4];
#pragma unroll
    for (int nt = 0; nt < 2; ++nt) {
      const int n = (w << 5) + (nt << 4) + il;
      bfr[nt] = *(const bf16x8*)(w2hi + (size_t)n * 256 + (ks << 5) + (q4 << 3));
    }
#pragma unroll
    for (int mt = 0; mt < 4; ++mt) {
      const int row = (mt << 4) + il;
      const int byte = (row << 9) + ((((ks << 5) + (q4 << 3)) << 1) ^ ((row & 7) << 4));
      afr[mt] = *(const bf16x8*)((const char*)h_lds + byte);
    }
#pragma unroll
    for (int mt = 0; mt < 4; ++mt)
#pragma unroll
      for (int nt = 0; nt < 2; ++nt)
        acc[mt][nt] = __builtin_amdgcn_mfma_f32_16x16x32_bf16(
            afr[mt], bfr[nt], acc[mt][nt], 0, 0, 0);
  }
#pragma unroll
  for (int nt = 0; nt < 2; ++nt) {
    const float bv = b2[(w << 5) + (nt << 4) + il];
#pragma unroll
    for (int mt = 0; mt < 4; ++mt)
#pragma unroll
      for (int r = 0; r < 4; ++r) acc[mt][nt][r] += bv;
  }

  const size_t kvbase = (size_t)(b << 12) * 256;

  // ---- phase 3: scores (one head per wave)
#pragma unroll
  for (int mt = 0; mt < 4; ++mt) {
    const int pt = mt >> 1;
#pragma unroll
    for (int r = 0; r < 4; ++r) {
      const int k = ((mt & 1) << 4) + (q4 << 2) + r;
      const int j = nbr[pt][k];
      const float* krow = kbuf + kvbase + (size_t)j * 256;
      float s = 0.f;
#pragma unroll
      for (int nt = 0; nt < 2; ++nt) {
        const int d = (w << 5) + (nt << 4) + il;
        s += q_lds[(pt << 8) + d] * (krow[d] + acc[mt][nt][r]);
      }
#pragma unroll
      for (int off = 1; off <= 8; off <<= 1) s += __shfl_xor(s, off);
      if (il == 0) sc_lds[pt][k][w] = s * SCALE_F;
    }
  }
  __syncthreads();

  // ---- phase 4: softmax over K=32 per (pt, head); 512 threads cover all
  {
    const int kk = tid & 31;
    const int head = (tid >> 5) & 7;
    const int pt = tid >> 8;
    const float val = sc_lds[pt][kk][head];
    float m = val;
#pragma unroll
    for (int off = 16; off; off >>= 1) m = fmaxf(m, __shfl_xor(m, off));
    const float e = __expf(val - m);
    float ssum = e;
#pragma unroll
    for (int off = 16; off; off >>= 1) ssum += __shfl_xor(ssum, off);
    at_lds[pt][kk][head] = e / ssum;
  }
  __syncthreads();

  // ---- phase 5: out = sum_k attn * (v_nei + pb)
  float o[2][2];
#pragma unroll
  for (int pt = 0; pt < 2; ++pt)
#pragma unroll
    for (int nt = 0; nt < 2; ++nt) o[pt][nt] = 0.f;
#pragma unroll
  for (int mt = 0; mt < 4; ++mt) {
    const int pt = mt >> 1;
#pragma unroll
    for (int r = 0; r < 4; ++r) {
      const int k = ((mt & 1) << 4) + (q4 << 2) + r;
      const int j = nbr[pt][k];
      const float* vrow = vbuf + kvbase + (size_t)j * 256;
      const float aw = at_lds[pt][k][w];
#pragma unroll
      for (int nt = 0; nt < 2; ++nt) {
        const int d = (w << 5) + (nt << 4) + il;
        o[pt][nt] += aw * (vrow[d] + acc[mt][nt][r]);
      }
    }
  }
#pragma unroll
  for (int pt = 0; pt < 2; ++pt)
#pragma unroll
    for (int nt = 0; nt < 2; ++nt) {
      float v = o[pt][nt];
      v += __shfl_xor(v, 16);
      v += __shfl_xor(v, 32);
      if (q4 == 0)
        o_pre[(size_t)(g0 + pt) * 256 + (w << 5) + (nt << 4) + il] = v;
    }
}

// ---------------------------------------------------------------------------
extern "C" void kernel_launch(void* const* d_in, const int* in_sizes, int n_in,
                              void* d_out, int out_size, void* d_ws, size_t ws_size,
                              hipStream_t stream) {
  (void)in_sizes; (void)n_in; (void)out_size; (void)ws_size;
  const float* xyz   = (const float*)d_in[0];
  const float* feats = (const float*)d_in[1];
  const float* Wq    = (const float*)d_in[2];
  const float* Wk    = (const float*)d_in[3];
  const float* Wv    = (const float*)d_in[4];
  const float* Wp    = (const float*)d_in[5];
  const float* bp    = (const float*)d_in[6];
  const float* W1    = (const float*)d_in[7];
  const float* b1    = (const float*)d_in[8];
  const float* W2    = (const float*)d_in[9];
  const float* b2    = (const float*)d_in[10];
  float* out = (float*)d_out;

  // ws floats: [idx:262144][q:2M][k:2M][v:2M][op:2M][whi:163840][wlo:163840]
  int* idxw  = (int*)d_ws;
  float* wsf = (float*)d_ws;
  float* qb = wsf + 262144;
  float* kb = qb + 2097152;
  float* vb = kb + 2097152;
  float* op = vb + 2097152;
  unsigned short* whi = (unsigned short*)(op + 2097152);
  unsigned short* wlo = whi + 327680;

  hipLaunchKernelGGL(prep_w, dim3(1280), dim3(256), 0, stream,
                     Wq, Wk, Wv, W2, Wp, whi, wlo);
  hipLaunchKernelGGL(knn_kernel, dim3(2 * PB), dim3(64), 0, stream, xyz, idxw);
  hipLaunchKernelGGL(qkv_mfma, dim3(768), dim3(256), 0, stream,
                     feats, whi, wlo, qb, kb, vb);
  hipLaunchKernelGGL(fused_kernel, dim3(PB), dim3(512), 0, stream,
                     xyz, idxw, qb, kb, vb, W1, b1,
                     whi + (size_t)3 * 65536, b2, op);
  hipLaunchKernelGGL(proj_mfma, dim3(256), dim3(256), 0, stream,
                     op, whi + (size_t)4 * 65536, wlo + (size_t)4 * 65536, bp, out);
}